// Round 8
// baseline (398.446 us; speedup 1.0000x reference)
//
#include <hip/hip_runtime.h>
#include <cmath>

#define N_CLASS 128
#define N_SUP   32
#define N_QRY   128
#define D_IN    2048
#define Z_DIM   1024
#define NPROTO  256
#define N_S     (N_CLASS * N_SUP)   // 4096
#define N_Q     (N_CLASS * N_QRY)   // 16384
#define N_ROWS  (N_S + N_Q)         // 20480

typedef __attribute__((ext_vector_type(4))) float f32x4;
typedef __attribute__((ext_vector_type(8))) short bf16x8;
typedef __attribute__((ext_vector_type(8))) unsigned short u16x8;
typedef _Float16 f16x8 __attribute__((ext_vector_type(8)));

__device__ __forceinline__ unsigned short f2bf(float f) {
    unsigned u = __float_as_uint(f);
    u += 0x7fffu + ((u >> 16) & 1u);   // RNE
    return (unsigned short)(u >> 16);
}

__device__ __forceinline__ void load_lds16(const void* g, void* l) {
    __builtin_amdgcn_global_load_lds(
        (const __attribute__((address_space(1))) unsigned int*)g,
        (__attribute__((address_space(3))) unsigned int*)l, 16, 0, 0);
}

// -------- cast fp32 -> bf16, 8 floats/thread, 16B stores, grid-stride --------
__global__ __launch_bounds__(256) void cast_all(
    const float* __restrict__ xs, const float* __restrict__ xq,
    unsigned short* __restrict__ out)
{
    const int nchunk = N_ROWS * D_IN / 8;           // 5,242,880 (8-elem chunks)
    for (int ch = blockIdx.x * 256 + threadIdx.x; ch < nchunk;
         ch += gridDim.x * 256) {
        const int i = ch * 8;                       // N_S*D_IN is chunk-aligned
        const float* src = (i < N_S * D_IN) ? (xs + i) : (xq + (i - N_S * D_IN));
        float4 a = *(const float4*)src;
        float4 b = *(const float4*)(src + 4);
        u16x8 o;
        o[0] = f2bf(a.x); o[1] = f2bf(a.y); o[2] = f2bf(a.z); o[3] = f2bf(a.w);
        o[4] = f2bf(b.x); o[5] = f2bf(b.y); o[6] = f2bf(b.z); o[7] = f2bf(b.w);
        *(u16x8*)(out + i) = o;                     // 16B store
    }
}

// ---------------- W (K x N fp32) -> Wt (N x K bf16), tiled transpose ----------
__global__ __launch_bounds__(256) void wt_kernel(
    const float* __restrict__ W, unsigned short* __restrict__ wt)
{
    __shared__ unsigned short t[64][65];
    const int n0 = blockIdx.x * 64;
    const int k0 = blockIdx.y * 64;
#pragma unroll
    for (int e = 0; e < 16; ++e) {
        int idx = e * 256 + threadIdx.x;
        int r = idx >> 6, c = idx & 63;            // r: k, c: n
        t[c][r] = f2bf(W[(size_t)(k0 + r) * Z_DIM + n0 + c]);
    }
    __syncthreads();
#pragma unroll
    for (int e = 0; e < 16; ++e) {
        int idx = e * 256 + threadIdx.x;
        int r = idx >> 6, c = idx & 63;            // r: n, c: k
        wt[(size_t)(n0 + r) * D_IN + k0 + c] = t[r][c];
    }
}

// ------- bf16 MFMA GEMM: z_h[20480x1024](f16) = xb @ WtT, + fused qnorm -------
// v5 (verified r7: 117 us, conflicts 0): counted-vmcnt 3-buffer pipeline +
// verified swizzle pair. UNCHANGED this round.
#define GBM 128
#define GBN 128
#define GBK 32

__global__ __launch_bounds__(256, 3) void gemm_mfma(
    const unsigned short* __restrict__ xb,   // 20480 x 2048 (row-major, bf16)
    const unsigned short* __restrict__ wt,   // 1024 x 2048 (N x K, bf16)
    _Float16* __restrict__ zh,               // 20480 x 1024 f16
    float* __restrict__ qnorm)               // 16384 (zero-initialized)
{
    __shared__ unsigned short sA[3][GBM * GBK];   // 3 x 8 KB
    __shared__ unsigned short sB[3][GBN * GBK];   // 3 x 8 KB
    const int tid  = threadIdx.x;

    // swizzle: b = 64g + 8j + k  ->  m-tile = 8g+k, n-tile = j
    const int b     = blockIdx.x + gridDim.x * blockIdx.y;
    const int m0    = ((b >> 6) * 8 + (b & 7)) * GBM;
    const int n0    = ((b >> 3) & 7) * GBN;

    const int lane = tid & 63;
    const int wave = tid >> 6;
    const int wm   = (wave >> 1) * 64;
    const int wn   = (wave & 1) * 64;

    // staging: LDS chunk f (16B) holds global (row = f>>2, slot = (f&3)^((f>>3)&3))
    const int f0 = tid, f1 = tid + 256;
    const int s0 = ((f0 & 3) ^ ((f0 >> 3) & 3)) << 3;
    const int s1 = ((f1 & 3) ^ ((f1 >> 3) & 3)) << 3;
    const unsigned short* ga0 = xb + (size_t)(m0 + (f0 >> 2)) * D_IN + s0;
    const unsigned short* ga1 = xb + (size_t)(m0 + (f1 >> 2)) * D_IN + s1;
    const unsigned short* gb0 = wt + (size_t)(n0 + (f0 >> 2)) * D_IN + s0;
    const unsigned short* gb1 = wt + (size_t)(n0 + (f1 >> 2)) * D_IN + s1;

    f32x4 acc[4][4];
#pragma unroll
    for (int i = 0; i < 4; ++i)
#pragma unroll
        for (int j = 0; j < 4; ++j) acc[i][j] = (f32x4){0.f, 0.f, 0.f, 0.f};

    const int ra = wm + (lane & 15);
    const int rb = wn + (lane & 15);
    // read-side swizzle (verified: bank conflicts -> 0)
    const int xo = (((lane >> 4) ^ ((lane >> 1) & 3)) << 3);

    auto stage = [&](int t) {
        const int buf = t % 3;
        const int k = t * GBK;
        load_lds16(ga0 + k, &sA[buf][f0 * 8]);
        load_lds16(ga1 + k, &sA[buf][f1 * 8]);
        load_lds16(gb0 + k, &sB[buf][f0 * 8]);
        load_lds16(gb1 + k, &sB[buf][f1 * 8]);
    };
    auto compute = [&](int buf) {
        bf16x8 af[4], bfr[4];
#pragma unroll
        for (int i = 0; i < 4; ++i)
            af[i] = *(const bf16x8*)&sA[buf][(ra + i * 16) * GBK + xo];
#pragma unroll
        for (int j = 0; j < 4; ++j)
            bfr[j] = *(const bf16x8*)&sB[buf][(rb + j * 16) * GBK + xo];
        __builtin_amdgcn_s_setprio(1);
#pragma unroll
        for (int i = 0; i < 4; ++i)
#pragma unroll
            for (int j = 0; j < 4; ++j)
                acc[i][j] = __builtin_amdgcn_mfma_f32_16x16x32_bf16(
                    af[i], bfr[j], acc[i][j], 0, 0, 0);
        __builtin_amdgcn_s_setprio(0);
    };

    stage(0);
    stage(1);
    asm volatile("s_waitcnt vmcnt(4)" ::: "memory");
    __builtin_amdgcn_s_barrier();
    __builtin_amdgcn_sched_barrier(0);

#pragma unroll 1
    for (int t = 0; t < (D_IN / GBK) - 2; ++t) {   // t = 0..61
        stage(t + 2);
        compute(t % 3);
        asm volatile("s_waitcnt vmcnt(4)" ::: "memory");
        __builtin_amdgcn_s_barrier();
        __builtin_amdgcn_sched_barrier(0);
    }
    compute(2);                                     // tile 62
    asm volatile("s_waitcnt vmcnt(0)" ::: "memory");
    __builtin_amdgcn_s_barrier();
    __builtin_amdgcn_sched_barrier(0);
    compute(0);                                     // tile 63

    // epilogue: f16 store + fused row-norm (query rows only)
#pragma unroll
    for (int i = 0; i < 4; ++i) {
#pragma unroll
        for (int r = 0; r < 4; ++r) {
            const int m = m0 + wm + i * 16 + (lane >> 4) * 4 + r;
#pragma unroll
            for (int j = 0; j < 4; ++j) {
                const int n = n0 + wn + j * 16 + (lane & 15);
                zh[(size_t)m * Z_DIM + n] = (_Float16)acc[i][j][r];
            }
            float p = acc[i][0][r] * acc[i][0][r] + acc[i][1][r] * acc[i][1][r]
                    + acc[i][2][r] * acc[i][2][r] + acc[i][3][r] * acc[i][3][r];
            p += __shfl_xor(p, 1);
            p += __shfl_xor(p, 2);
            p += __shfl_xor(p, 4);
            p += __shfl_xor(p, 8);
            if (m >= N_S && (lane & 15) == 0) atomicAdd(&qnorm[m - N_S], p);
        }
    }
}

// ---- assignment (r0 faithful revert): one wave per support row ---------------
__global__ __launch_bounds__(256) void assign_kernel(
    const _Float16* __restrict__ zh, int* __restrict__ assign)
{
    const int wave = threadIdx.x >> 6, lane = threadIdx.x & 63;
    const int sg = blockIdx.x * 4 + wave;       // 0..4095
    const int c  = sg >> 5;
    const _Float16* zc = zh + (size_t)c * N_SUP * Z_DIM;
    const _Float16* zr = zc + (size_t)(sg & 31) * Z_DIM;
    float d0 = 0.f, d1 = 0.f;
#pragma unroll
    for (int it = 0; it < 2; ++it) {
        const int idx = (it * 64 + lane) * 8;
        f16x8 v  = *(const f16x8*)(zr + idx);
        f16x8 i0 = *(const f16x8*)(zc + idx);
        f16x8 i1 = *(const f16x8*)(zc + Z_DIM + idx);
#pragma unroll
        for (int e = 0; e < 8; ++e) {
            float t0 = (float)v[e] - (float)i0[e];
            float t1 = (float)v[e] - (float)i1[e];
            d0 = fmaf(t0, t0, d0);
            d1 = fmaf(t1, t1, d1);
        }
    }
    for (int off = 32; off; off >>= 1) {
        d0 += __shfl_down(d0, off);
        d1 += __shfl_down(d1, off);
    }
    if (lane == 0) assign[sg] = (d1 < d0) ? 1 : 0;
}

// ---- centroids (r0 faithful revert): block = (d-chunk, class) ----------------
__global__ __launch_bounds__(256) void centroid_kernel(
    const _Float16* __restrict__ zh, const int* __restrict__ assign,
    _Float16* __restrict__ ph, float* __restrict__ pnorm)   // pnorm zero-init
{
    const int c = blockIdx.y;
    const int d = blockIdx.x * 256 + threadIdx.x;
    __shared__ int sa_[N_SUP];
    if (threadIdx.x < N_SUP) sa_[threadIdx.x] = assign[c * N_SUP + threadIdx.x];
    __syncthreads();
    int cnt1 = 0;
#pragma unroll
    for (int s = 0; s < N_SUP; ++s) cnt1 += sa_[s];
    const int cnt0 = N_SUP - cnt1;

    const _Float16* zc = zh + (size_t)c * N_SUP * Z_DIM;
    float s0 = 0.f, s1 = 0.f;
#pragma unroll
    for (int s = 0; s < N_SUP; ++s) {
        float v = (float)zc[(size_t)s * Z_DIM + d];
        if (sa_[s]) s1 += v; else s0 += v;
    }
    float c0 = (cnt0 > 0) ? (s0 / (float)cnt0) : (float)zc[d];
    float c1 = (cnt1 > 0) ? (s1 / (float)cnt1) : (float)zc[Z_DIM + d];
    ph[(size_t)(2 * c)     * Z_DIM + d] = (_Float16)c0;
    ph[(size_t)(2 * c + 1) * Z_DIM + d] = (_Float16)c1;

    float n0 = c0 * c0, n1 = c1 * c1;
    for (int off = 32; off; off >>= 1) {
        n0 += __shfl_down(n0, off);
        n1 += __shfl_down(n1, off);
    }
    if ((threadIdx.x & 63) == 0) {
        atomicAdd(&pnorm[2 * c],     n0);
        atomicAdd(&pnorm[2 * c + 1], n1);
    }
}

// ---- fused dist + per-query reduce + LAST-BLOCK FINALIZE ---------------------
// v3: counted-vmcnt 3-buffer pipeline (pattern verified in gemm v5) + verified
// swizzle pair (same 64B-row / 4x16B-chunk geometry) + device-scope accum with
// last-block-done finalize (deletes the finalize kernel).
// Wave-divergent load counts: waves 0-1 issue 5 loads/step (A+4B), waves 2-3
// issue 4 (B only) -> wave-uniform vmcnt(5)/vmcnt(4) branch before barrier.
#define TBM 32
#define TBN 256
#define TBK 32
__global__ __launch_bounds__(256) void distred_kernel(
    const _Float16* __restrict__ zqh,   // 16384 x 1024
    const _Float16* __restrict__ ph,    // 256 x 1024 (N x K)
    const float* __restrict__ pnorm, const float* __restrict__ qnorm,
    float* __restrict__ accum,          // [2] zero-init: L, A
    unsigned* __restrict__ counter,     // zero-init
    float* __restrict__ out)
{
    __shared__ _Float16 sA[3][TBM * TBK];  //  6 KB
    __shared__ _Float16 sB[3][TBN * TBK];  // 48 KB
    __shared__ float sD[TBM][N_CLASS + 1]; // 16.5 KB (pad breaks write conflicts)
    __shared__ float swl[4], swa[4];
    const int tid  = threadIdx.x;
    const int lane = tid & 63;
    const int wave = tid >> 6;
    const int q0   = blockIdx.x * TBM;
    const int wn   = wave * 64;            // each wave: all 32 rows x 64 cols

    // staging (swizzled source slot, linear LDS dest — verified pair):
    // chunk f: row = f>>2, slot = (f&3)^((f>>3)&3)
    const int sw0 = ((tid & 3) ^ ((tid >> 3) & 3)) << 3;
    const _Float16* ga = zqh + (size_t)(q0 + (tid >> 2)) * Z_DIM + sw0;  // tid<128
    const _Float16* gb[4];
#pragma unroll
    for (int i = 0; i < 4; ++i) {
        const int f = tid + 256 * i;
        const int s = ((f & 3) ^ ((f >> 3) & 3)) << 3;
        gb[i] = ph + (size_t)(f >> 2) * Z_DIM + s;
    }

    f32x4 acc[2][4];
#pragma unroll
    for (int i = 0; i < 2; ++i)
#pragma unroll
        for (int j = 0; j < 4; ++j) acc[i][j] = (f32x4){0.f, 0.f, 0.f, 0.f};

    const int rf = lane & 15;
    const int xo = (((lane >> 4) ^ ((lane >> 1) & 3)) << 3);   // swizzled read

    auto stage = [&](int t) {
        const int buf = t % 3;
        const int k = t * TBK;
        if (tid < 128) load_lds16(ga + k, &sA[buf][tid * 8]);
#pragma unroll
        for (int i = 0; i < 4; ++i)
            load_lds16(gb[i] + k, &sB[buf][(tid + 256 * i) * 8]);
    };
    auto compute = [&](int buf) {
        f16x8 af[2], bfr[4];
#pragma unroll
        for (int i = 0; i < 2; ++i)
            af[i] = *(const f16x8*)&sA[buf][(i * 16 + rf) * TBK + xo];
#pragma unroll
        for (int j = 0; j < 4; ++j)
            bfr[j] = *(const f16x8*)&sB[buf][(wn + j * 16 + rf) * TBK + xo];
        __builtin_amdgcn_s_setprio(1);
#pragma unroll
        for (int i = 0; i < 2; ++i)
#pragma unroll
            for (int j = 0; j < 4; ++j)
                acc[i][j] = __builtin_amdgcn_mfma_f32_16x16x32_f16(
                    af[i], bfr[j], acc[i][j], 0, 0, 0);
        __builtin_amdgcn_s_setprio(0);
    };
    auto wait_tile = [&]() {
        if (wave < 2) asm volatile("s_waitcnt vmcnt(5)" ::: "memory");
        else          asm volatile("s_waitcnt vmcnt(4)" ::: "memory");
        __builtin_amdgcn_s_barrier();
        __builtin_amdgcn_sched_barrier(0);
    };

    stage(0);
    stage(1);
    wait_tile();
#pragma unroll 1
    for (int t = 0; t < (Z_DIM / TBK) - 2; ++t) {   // t = 0..29
        stage(t + 2);
        compute(t % 3);
        wait_tile();
    }
    compute(0);                                      // tile 30 (30%3==0)
    asm volatile("s_waitcnt vmcnt(0)" ::: "memory");
    __builtin_amdgcn_s_barrier();
    __builtin_amdgcn_sched_barrier(0);
    compute(1);                                      // tile 31 (31%3==1)

    // epilogue 1: dists into LDS (pair-min over K=2)
    float pn[4];
#pragma unroll
    for (int j = 0; j < 4; ++j) pn[j] = pnorm[wn + j * 16 + rf];
#pragma unroll
    for (int i = 0; i < 2; ++i) {
#pragma unroll
        for (int r = 0; r < 4; ++r) {
            const int row = i * 16 + (lane >> 4) * 4 + r;
            const float qn = qnorm[q0 + row];
#pragma unroll
            for (int j = 0; j < 4; ++j) {
                float d = fmaxf(qn + pn[j] - 2.f * acc[i][j][r], 0.f);
                float o = __shfl_xor(d, 1);
                if (!(lane & 1))
                    sD[row][(wn >> 1) + j * 8 + (rf >> 1)] = fminf(d, o);
            }
        }
    }
    __syncthreads();

    // epilogue 2: per-row sum/argmax/own; 8 rows per wave
    float L = 0.f, A = 0.f;
#pragma unroll
    for (int rr = 0; rr < 8; ++rr) {
        const int row = wave * 8 + rr;
        const float va = sD[row][lane];
        const float vb = sD[row][lane + 64];
        float sum = va + vb;
        float bv; int bi;
        if (vb > va) { bv = vb; bi = lane + 64; } else { bv = va; bi = lane; }
        for (int off = 32; off; off >>= 1) {
            sum += __shfl_down(sum, off);
            float ov = __shfl_down(bv, off);
            int   oi = __shfl_down(bi, off);
            if (ov > bv || (ov == bv && oi < bi)) { bv = ov; bi = oi; }
        }
        if (lane == 0) {
            const int c = (q0 + row) >> 7;
            L += logf(sD[row][c] / sum);
            A += (bi == c) ? 1.f : 0.f;
        }
    }
    if (lane == 0) { swl[wave] = L; swa[wave] = A; }
    __syncthreads();

    // last-block finalize (device-scope atomics + fence + counter)
    if (tid == 0) {
        const float Ls = swl[0] + swl[1] + swl[2] + swl[3];
        const float As = swa[0] + swa[1] + swa[2] + swa[3];
        atomicAdd(&accum[0], Ls);
        atomicAdd(&accum[1], As);
        __threadfence();
        const unsigned n = atomicAdd(counter, 1u);
        if (n == gridDim.x - 1) {
            const float Lt = atomicAdd(&accum[0], 0.f);   // atomic read
            const float At = atomicAdd(&accum[1], 0.f);
            out[0] = -Lt / (float)N_Q;
            out[1] =  At / (float)N_Q;
        }
    }
}

// ---------------- launch ----------------
extern "C" void kernel_launch(void* const* d_in, const int* in_sizes, int n_in,
                              void* d_out, int out_size, void* d_ws, size_t ws_size,
                              hipStream_t stream)
{
    (void)in_sizes; (void)n_in; (void)out_size; (void)ws_size;
    const float* xs = (const float*)d_in[0];
    const float* xq = (const float*)d_in[1];
    const float* W  = (const float*)d_in[2];
    float* out = (float*)d_out;

    char* ws = (char*)d_ws;
    _Float16*       zh     = (_Float16*)(ws);                     //  41,943,040 B
    unsigned short* xb     = (unsigned short*)(ws + 41943040ull); //  83,886,080 B
    unsigned short* wt     = (unsigned short*)(ws + 125829120ull);//   4,194,304 B
    _Float16*       ph     = (_Float16*)(ws + 130023424ull);      //     524,288 B
    float*          pnorm  = (float*)(ws + 130547712ull);         //       1,024 B
    float*          qnorm  = (float*)(ws + 130548736ull);         //      65,536 B
    float*          accum  = (float*)(ws + 130614272ull);         //           8 B
    unsigned*       counter= (unsigned*)(ws + 130614280ull);      //           4 B
    int*            assign = (int*)(ws + 130614288ull);           //      16,384 B

    cast_all<<<2048, 256, 0, stream>>>(xs, xq, xb);
    wt_kernel<<<dim3(Z_DIM / 64, D_IN / 64), 256, 0, stream>>>(W, wt);
    // zero pnorm + qnorm + accum + counter in one contiguous memset
    hipMemsetAsync(pnorm, 0, 1024 + N_Q * sizeof(float) + 12, stream);

    dim3 gA(Z_DIM / GBN, N_ROWS / GBM);   // (8, 160) -> swizzled in-kernel
    gemm_mfma<<<gA, 256, 0, stream>>>(xb, wt, zh, qnorm);

    assign_kernel<<<N_S / 4, 256, 0, stream>>>(zh, assign);
    centroid_kernel<<<dim3(Z_DIM / 256, N_CLASS), 256, 0, stream>>>(zh, assign, ph, pnorm);

    const _Float16* zqh = zh + (size_t)N_S * Z_DIM;
    distred_kernel<<<N_Q / TBM, 256, 0, stream>>>(zqh, ph, pnorm, qnorm,
                                                  accum, counter, out);
}

// Round 9
// 375.133 us; speedup vs baseline: 1.0621x; 1.0621x over previous
//
#include <hip/hip_runtime.h>
#include <cmath>

#define N_CLASS 128
#define N_SUP   32
#define N_QRY   128
#define D_IN    2048
#define Z_DIM   1024
#define NPROTO  256
#define N_S     (N_CLASS * N_SUP)   // 4096
#define N_Q     (N_CLASS * N_QRY)   // 16384
#define N_ROWS  (N_S + N_Q)         // 20480

typedef __attribute__((ext_vector_type(4))) float f32x4;
typedef __attribute__((ext_vector_type(8))) short bf16x8;
typedef __attribute__((ext_vector_type(8))) unsigned short u16x8;
typedef _Float16 f16x8 __attribute__((ext_vector_type(8)));

__device__ __forceinline__ unsigned short f2bf(float f) {
    unsigned u = __float_as_uint(f);
    u += 0x7fffu + ((u >> 16) & 1u);   // RNE
    return (unsigned short)(u >> 16);
}

__device__ __forceinline__ void load_lds16(const void* g, void* l) {
    __builtin_amdgcn_global_load_lds(
        (const __attribute__((address_space(1))) unsigned int*)g,
        (__attribute__((address_space(3))) unsigned int*)l, 16, 0, 0);
}

// -------- cast fp32 -> bf16: direct-index, 8 floats/thread, 16B stores -------
// (cast_new minus grid-stride loop; isolates the loop-overhead hypothesis)
__global__ __launch_bounds__(256) void cast_all(
    const float* __restrict__ xs, const float* __restrict__ xq,
    unsigned short* __restrict__ out)
{
    const int i = (blockIdx.x * 256 + threadIdx.x) * 8;
    const float* src = (i < N_S * D_IN) ? (xs + i) : (xq + (i - N_S * D_IN));
    float4 a = *(const float4*)src;
    float4 b = *(const float4*)(src + 4);
    u16x8 o;
    o[0] = f2bf(a.x); o[1] = f2bf(a.y); o[2] = f2bf(a.z); o[3] = f2bf(a.w);
    o[4] = f2bf(b.x); o[5] = f2bf(b.y); o[6] = f2bf(b.z); o[7] = f2bf(b.w);
    *(u16x8*)(out + i) = o;                     // 16B store
}

// ---------------- W (K x N fp32) -> Wt (N x K bf16), tiled transpose ----------
__global__ __launch_bounds__(256) void wt_kernel(
    const float* __restrict__ W, unsigned short* __restrict__ wt)
{
    __shared__ unsigned short t[64][65];
    const int n0 = blockIdx.x * 64;
    const int k0 = blockIdx.y * 64;
#pragma unroll
    for (int e = 0; e < 16; ++e) {
        int idx = e * 256 + threadIdx.x;
        int r = idx >> 6, c = idx & 63;            // r: k, c: n
        t[c][r] = f2bf(W[(size_t)(k0 + r) * Z_DIM + n0 + c]);
    }
    __syncthreads();
#pragma unroll
    for (int e = 0; e < 16; ++e) {
        int idx = e * 256 + threadIdx.x;
        int r = idx >> 6, c = idx & 63;            // r: n, c: k
        wt[(size_t)(n0 + r) * D_IN + k0 + c] = t[r][c];
    }
}

// ------- bf16 MFMA GEMM: z_h[20480x1024](f16) = xb @ WtT, + fused qnorm -------
// v5 (verified r7/r8: 117-118.6 us, conflicts 0): counted-vmcnt 3-buffer
// pipeline + verified swizzle pair. UNCHANGED.
#define GBM 128
#define GBN 128
#define GBK 32

__global__ __launch_bounds__(256, 3) void gemm_mfma(
    const unsigned short* __restrict__ xb,   // 20480 x 2048 (row-major, bf16)
    const unsigned short* __restrict__ wt,   // 1024 x 2048 (N x K, bf16)
    _Float16* __restrict__ zh,               // 20480 x 1024 f16
    float* __restrict__ qnorm)               // 16384 (zero-initialized)
{
    __shared__ unsigned short sA[3][GBM * GBK];   // 3 x 8 KB
    __shared__ unsigned short sB[3][GBN * GBK];   // 3 x 8 KB
    const int tid  = threadIdx.x;

    // swizzle: b = 64g + 8j + k  ->  m-tile = 8g+k, n-tile = j
    const int b     = blockIdx.x + gridDim.x * blockIdx.y;
    const int m0    = ((b >> 6) * 8 + (b & 7)) * GBM;
    const int n0    = ((b >> 3) & 7) * GBN;

    const int lane = tid & 63;
    const int wave = tid >> 6;
    const int wm   = (wave >> 1) * 64;
    const int wn   = (wave & 1) * 64;

    // staging: LDS chunk f (16B) holds global (row = f>>2, slot = (f&3)^((f>>3)&3))
    const int f0 = tid, f1 = tid + 256;
    const int s0 = ((f0 & 3) ^ ((f0 >> 3) & 3)) << 3;
    const int s1 = ((f1 & 3) ^ ((f1 >> 3) & 3)) << 3;
    const unsigned short* ga0 = xb + (size_t)(m0 + (f0 >> 2)) * D_IN + s0;
    const unsigned short* ga1 = xb + (size_t)(m0 + (f1 >> 2)) * D_IN + s1;
    const unsigned short* gb0 = wt + (size_t)(n0 + (f0 >> 2)) * D_IN + s0;
    const unsigned short* gb1 = wt + (size_t)(n0 + (f1 >> 2)) * D_IN + s1;

    f32x4 acc[4][4];
#pragma unroll
    for (int i = 0; i < 4; ++i)
#pragma unroll
        for (int j = 0; j < 4; ++j) acc[i][j] = (f32x4){0.f, 0.f, 0.f, 0.f};

    const int ra = wm + (lane & 15);
    const int rb = wn + (lane & 15);
    // read-side swizzle (verified: bank conflicts -> 0)
    const int xo = (((lane >> 4) ^ ((lane >> 1) & 3)) << 3);

    auto stage = [&](int t) {
        const int buf = t % 3;
        const int k = t * GBK;
        load_lds16(ga0 + k, &sA[buf][f0 * 8]);
        load_lds16(ga1 + k, &sA[buf][f1 * 8]);
        load_lds16(gb0 + k, &sB[buf][f0 * 8]);
        load_lds16(gb1 + k, &sB[buf][f1 * 8]);
    };
    auto compute = [&](int buf) {
        bf16x8 af[4], bfr[4];
#pragma unroll
        for (int i = 0; i < 4; ++i)
            af[i] = *(const bf16x8*)&sA[buf][(ra + i * 16) * GBK + xo];
#pragma unroll
        for (int j = 0; j < 4; ++j)
            bfr[j] = *(const bf16x8*)&sB[buf][(rb + j * 16) * GBK + xo];
        __builtin_amdgcn_s_setprio(1);
#pragma unroll
        for (int i = 0; i < 4; ++i)
#pragma unroll
            for (int j = 0; j < 4; ++j)
                acc[i][j] = __builtin_amdgcn_mfma_f32_16x16x32_bf16(
                    af[i], bfr[j], acc[i][j], 0, 0, 0);
        __builtin_amdgcn_s_setprio(0);
    };

    stage(0);
    stage(1);
    asm volatile("s_waitcnt vmcnt(4)" ::: "memory");
    __builtin_amdgcn_s_barrier();
    __builtin_amdgcn_sched_barrier(0);

#pragma unroll 1
    for (int t = 0; t < (D_IN / GBK) - 2; ++t) {   // t = 0..61
        stage(t + 2);
        compute(t % 3);
        asm volatile("s_waitcnt vmcnt(4)" ::: "memory");
        __builtin_amdgcn_s_barrier();
        __builtin_amdgcn_sched_barrier(0);
    }
    compute(2);                                     // tile 62
    asm volatile("s_waitcnt vmcnt(0)" ::: "memory");
    __builtin_amdgcn_s_barrier();
    __builtin_amdgcn_sched_barrier(0);
    compute(0);                                     // tile 63

    // epilogue: f16 store + fused row-norm (query rows only)
#pragma unroll
    for (int i = 0; i < 4; ++i) {
#pragma unroll
        for (int r = 0; r < 4; ++r) {
            const int m = m0 + wm + i * 16 + (lane >> 4) * 4 + r;
#pragma unroll
            for (int j = 0; j < 4; ++j) {
                const int n = n0 + wn + j * 16 + (lane & 15);
                zh[(size_t)m * Z_DIM + n] = (_Float16)acc[i][j][r];
            }
            float p = acc[i][0][r] * acc[i][0][r] + acc[i][1][r] * acc[i][1][r]
                    + acc[i][2][r] * acc[i][2][r] + acc[i][3][r] * acc[i][3][r];
            p += __shfl_xor(p, 1);
            p += __shfl_xor(p, 2);
            p += __shfl_xor(p, 4);
            p += __shfl_xor(p, 8);
            if (m >= N_S && (lane & 15) == 0) atomicAdd(&qnorm[m - N_S], p);
        }
    }
}

// ---- assignment (r0 exact): one wave per support row -------------------------
__global__ __launch_bounds__(256) void assign_kernel(
    const _Float16* __restrict__ zh, int* __restrict__ assign)
{
    const int wave = threadIdx.x >> 6, lane = threadIdx.x & 63;
    const int sg = blockIdx.x * 4 + wave;       // 0..4095
    const int c  = sg >> 5;
    const _Float16* zc = zh + (size_t)c * N_SUP * Z_DIM;
    const _Float16* zr = zc + (size_t)(sg & 31) * Z_DIM;
    float d0 = 0.f, d1 = 0.f;
#pragma unroll
    for (int it = 0; it < 2; ++it) {
        const int idx = (it * 64 + lane) * 8;
        f16x8 v  = *(const f16x8*)(zr + idx);
        f16x8 i0 = *(const f16x8*)(zc + idx);
        f16x8 i1 = *(const f16x8*)(zc + Z_DIM + idx);
#pragma unroll
        for (int e = 0; e < 8; ++e) {
            float t0 = (float)v[e] - (float)i0[e];
            float t1 = (float)v[e] - (float)i1[e];
            d0 = fmaf(t0, t0, d0);
            d1 = fmaf(t1, t1, d1);
        }
    }
    for (int off = 32; off; off >>= 1) {
        d0 += __shfl_down(d0, off);
        d1 += __shfl_down(d1, off);
    }
    if (lane == 0) assign[sg] = (d1 < d0) ? 1 : 0;
}

// ---- centroids (r0 exact): block = (d-chunk, class) --------------------------
__global__ __launch_bounds__(256) void centroid_kernel(
    const _Float16* __restrict__ zh, const int* __restrict__ assign,
    _Float16* __restrict__ ph, float* __restrict__ pnorm)   // pnorm zero-init
{
    const int c = blockIdx.y;
    const int d = blockIdx.x * 256 + threadIdx.x;
    __shared__ int sa_[N_SUP];
    if (threadIdx.x < N_SUP) sa_[threadIdx.x] = assign[c * N_SUP + threadIdx.x];
    __syncthreads();
    int cnt1 = 0;
#pragma unroll
    for (int s = 0; s < N_SUP; ++s) cnt1 += sa_[s];
    const int cnt0 = N_SUP - cnt1;

    const _Float16* zc = zh + (size_t)c * N_SUP * Z_DIM;
    float s0 = 0.f, s1 = 0.f;
#pragma unroll
    for (int s = 0; s < N_SUP; ++s) {
        float v = (float)zc[(size_t)s * Z_DIM + d];
        if (sa_[s]) s1 += v; else s0 += v;
    }
    float c0 = (cnt0 > 0) ? (s0 / (float)cnt0) : (float)zc[d];
    float c1 = (cnt1 > 0) ? (s1 / (float)cnt1) : (float)zc[Z_DIM + d];
    ph[(size_t)(2 * c)     * Z_DIM + d] = (_Float16)c0;
    ph[(size_t)(2 * c + 1) * Z_DIM + d] = (_Float16)c1;

    float n0 = c0 * c0, n1 = c1 * c1;
    for (int off = 32; off; off >>= 1) {
        n0 += __shfl_down(n0, off);
        n1 += __shfl_down(n1, off);
    }
    if ((threadIdx.x & 63) == 0) {
        atomicAdd(&pnorm[2 * c],     n0);
        atomicAdd(&pnorm[2 * c + 1], n1);
    }
}

// ---- fused dist + per-query reduce (r0 exact): 32 queries x 256 protos -------
#define TBM 32
#define TBN 256
#define TBK 32
__global__ __launch_bounds__(256) void distred_kernel(
    const _Float16* __restrict__ zqh,   // 16384 x 1024
    const _Float16* __restrict__ ph,    // 256 x 1024 (N x K)
    const float* __restrict__ pnorm, const float* __restrict__ qnorm,
    float2* __restrict__ partial)       // 512
{
    __shared__ _Float16 sA[TBM * TBK];     //  2 KB
    __shared__ _Float16 sB[TBN * TBK];     // 16 KB
    __shared__ float sD[TBM][N_CLASS + 1]; // 16.1 KB (pad breaks write conflicts)
    __shared__ float swl[4], swa[4];
    const int tid  = threadIdx.x;
    const int lane = tid & 63;
    const int wave = tid >> 6;
    const int q0   = blockIdx.x * TBM;
    const int wn   = wave * 64;            // each wave: all 32 rows x 64 cols

    // staging: A = 128 chunks of 16B (threads 0..127); B = 1024 chunks (4/thread)
    const _Float16* ga = zqh + (size_t)(q0 + (tid >> 2)) * Z_DIM + ((tid & 3) << 3);
    _Float16* la = &sA[tid * 8];
    const _Float16* gb[4]; _Float16* lb[4];
#pragma unroll
    for (int i = 0; i < 4; ++i) {
        const int f = tid + 256 * i;
        gb[i] = ph + (size_t)(f >> 2) * Z_DIM + ((f & 3) << 3);
        lb[i] = &sB[f * 8];
    }

    f32x4 acc[2][4];
#pragma unroll
    for (int i = 0; i < 2; ++i)
#pragma unroll
        for (int j = 0; j < 4; ++j) acc[i][j] = (f32x4){0.f, 0.f, 0.f, 0.f};

    const int rf = lane & 15;
    const int ko = (lane >> 4) * 8;

    for (int k0 = 0; k0 < Z_DIM; k0 += TBK) {
        if (tid < 128) load_lds16(ga + k0, la);
#pragma unroll
        for (int i = 0; i < 4; ++i) load_lds16(gb[i] + k0, lb[i]);
        __syncthreads();
        f16x8 af[2], bfr[4];
#pragma unroll
        for (int i = 0; i < 2; ++i)
            af[i] = *(const f16x8*)&sA[(i * 16 + rf) * TBK + ko];
#pragma unroll
        for (int j = 0; j < 4; ++j)
            bfr[j] = *(const f16x8*)&sB[(wn + j * 16 + rf) * TBK + ko];
#pragma unroll
        for (int i = 0; i < 2; ++i)
#pragma unroll
            for (int j = 0; j < 4; ++j)
                acc[i][j] = __builtin_amdgcn_mfma_f32_16x16x32_f16(
                    af[i], bfr[j], acc[i][j], 0, 0, 0);
        __syncthreads();
    }

    // epilogue 1: dists into LDS (pair-min over K=2)
    float pn[4];
#pragma unroll
    for (int j = 0; j < 4; ++j) pn[j] = pnorm[wn + j * 16 + rf];
#pragma unroll
    for (int i = 0; i < 2; ++i) {
#pragma unroll
        for (int r = 0; r < 4; ++r) {
            const int row = i * 16 + (lane >> 4) * 4 + r;
            const float qn = qnorm[q0 + row];
#pragma unroll
            for (int j = 0; j < 4; ++j) {
                float d = fmaxf(qn + pn[j] - 2.f * acc[i][j][r], 0.f);
                float o = __shfl_xor(d, 1);
                if (!(lane & 1))
                    sD[row][(wn >> 1) + j * 8 + (rf >> 1)] = fminf(d, o);
            }
        }
    }
    __syncthreads();

    // epilogue 2: per-row sum/argmax/own; 8 rows per wave
    float L = 0.f, A = 0.f;
#pragma unroll
    for (int rr = 0; rr < 8; ++rr) {
        const int row = wave * 8 + rr;
        const float va = sD[row][lane];
        const float vb = sD[row][lane + 64];
        float sum = va + vb;
        float bv; int bi;
        if (vb > va) { bv = vb; bi = lane + 64; } else { bv = va; bi = lane; }
        for (int off = 32; off; off >>= 1) {
            sum += __shfl_down(sum, off);
            float ov = __shfl_down(bv, off);
            int   oi = __shfl_down(bi, off);
            if (ov > bv || (ov == bv && oi < bi)) { bv = ov; bi = oi; }
        }
        if (lane == 0) {
            const int c = (q0 + row) >> 7;
            L += logf(sD[row][c] / sum);
            A += (bi == c) ? 1.f : 0.f;
        }
    }
    if (lane == 0) { swl[wave] = L; swa[wave] = A; }
    __syncthreads();
    if (tid == 0)
        partial[blockIdx.x] = make_float2(swl[0] + swl[1] + swl[2] + swl[3],
                                          swa[0] + swa[1] + swa[2] + swa[3]);
}

// ---------------- final reduce over 512 partials (single block) ---------------
__global__ __launch_bounds__(512) void finalize_kernel(
    const float2* __restrict__ partial, float* __restrict__ out)
{
    __shared__ float sl[8], sa[8];
    const int tid = threadIdx.x;
    float2 p = partial[tid];
    float l = p.x, a = p.y;
    for (int off = 32; off; off >>= 1) {
        l += __shfl_down(l, off);
        a += __shfl_down(a, off);
    }
    const int lane = tid & 63, wave = tid >> 6;
    if (lane == 0) { sl[wave] = l; sa[wave] = a; }
    __syncthreads();
    if (tid == 0) {
        float L = 0.f, A = 0.f;
#pragma unroll
        for (int w = 0; w < 8; ++w) { L += sl[w]; A += sa[w]; }
        out[0] = -L / (float)N_Q;
        out[1] =  A / (float)N_Q;
    }
}

// ---------------- launch ----------------
extern "C" void kernel_launch(void* const* d_in, const int* in_sizes, int n_in,
                              void* d_out, int out_size, void* d_ws, size_t ws_size,
                              hipStream_t stream)
{
    (void)in_sizes; (void)n_in; (void)out_size; (void)ws_size;
    const float* xs = (const float*)d_in[0];
    const float* xq = (const float*)d_in[1];
    const float* W  = (const float*)d_in[2];
    float* out = (float*)d_out;

    char* ws = (char*)d_ws;
    _Float16*       zh     = (_Float16*)(ws);                     //  41,943,040 B
    unsigned short* xb     = (unsigned short*)(ws + 41943040ull); //  83,886,080 B
    unsigned short* wt     = (unsigned short*)(ws + 125829120ull);//   4,194,304 B
    _Float16*       ph     = (_Float16*)(ws + 130023424ull);      //     524,288 B
    float*          pnorm  = (float*)(ws + 130547712ull);         //       1,024 B
    float*          qnorm  = (float*)(ws + 130548736ull);         //      65,536 B
    float2*         partial= (float2*)(ws + 130614272ull);        //       4,096 B
    int*            assign = (int*)(ws + 130618368ull);           //      16,384 B

    cast_all<<<N_ROWS * D_IN / 2048, 256, 0, stream>>>(xs, xq, xb);  // 20480 blk
    wt_kernel<<<dim3(Z_DIM / 64, D_IN / 64), 256, 0, stream>>>(W, wt);
    hipMemsetAsync(pnorm, 0, 1024 + N_Q * sizeof(float), stream);  // pnorm+qnorm

    dim3 gA(Z_DIM / GBN, N_ROWS / GBM);   // (8, 160) -> swizzled in-kernel
    gemm_mfma<<<gA, 256, 0, stream>>>(xb, wt, zh, qnorm);

    assign_kernel<<<N_S / 4, 256, 0, stream>>>(zh, assign);
    centroid_kernel<<<dim3(Z_DIM / 256, N_CLASS), 256, 0, stream>>>(zh, assign, ph, pnorm);

    const _Float16* zqh = zh + (size_t)N_S * Z_DIM;
    distred_kernel<<<N_Q / TBM, 256, 0, stream>>>(zqh, ph, pnorm, qnorm, partial);

    finalize_kernel<<<1, 512, 0, stream>>>(partial, out);
}